// Round 2
// baseline (10904.575 us; speedup 1.0000x reference)
//
#include <hip/hip_runtime.h>
#include <math.h>

#define N_NODES 100000
#define N_EDGES 3200000
#define H 32

__device__ __forceinline__ float lrelu(float v) { return v > 0.0f ? v : 0.01f * v; }

// out = bias + in @ W   (W is [H,H] row-major: W[k*H+o]); uniform W/bias -> s_loads
__device__ __forceinline__ void matvec32(const float* __restrict__ in,
                                         const float* __restrict__ W,
                                         const float* __restrict__ bias,
                                         float* __restrict__ out) {
#pragma unroll
    for (int o = 0; o < H; ++o) out[o] = bias[o];
#pragma unroll
    for (int k = 0; k < H; ++k) {
        float v = in[k];
#pragma unroll
        for (int o = 0; o < H; ++o) out[o] = fmaf(v, W[k * H + o], out[o]);
    }
}

// out += in @ W
__device__ __forceinline__ void matvec32_acc(const float* __restrict__ in,
                                             const float* __restrict__ W,
                                             float* __restrict__ out) {
#pragma unroll
    for (int k = 0; k < H; ++k) {
        float v = in[k];
#pragma unroll
        for (int o = 0; o < H; ++o) out[o] = fmaf(v, W[k * H + o], out[o]);
    }
}

__device__ __forceinline__ void load_row32(const float* __restrict__ p, float* __restrict__ r) {
    const float4* p4 = reinterpret_cast<const float4*>(p);
#pragma unroll
    for (int q = 0; q < 8; ++q) {
        float4 v = p4[q];
        r[4 * q + 0] = v.x; r[4 * q + 1] = v.y; r[4 * q + 2] = v.z; r[4 * q + 3] = v.w;
    }
}

__device__ __forceinline__ void store_row32(float* __restrict__ p, const float* __restrict__ r) {
    float4* p4 = reinterpret_cast<float4*>(p);
#pragma unroll
    for (int q = 0; q < 8; ++q) {
        float4 v;
        v.x = r[4 * q + 0]; v.y = r[4 * q + 1]; v.z = r[4 * q + 2]; v.w = r[4 * q + 3];
        p4[q] = v;
    }
}

// h_node row for node i from x[i] (W_in is [3,H])
__device__ __forceinline__ void hnode_row(const float* __restrict__ x, int i,
                                          const float* __restrict__ W_in,
                                          const float* __restrict__ b_in,
                                          float* __restrict__ r) {
    float x0 = x[(size_t)i * 3 + 0], x1 = x[(size_t)i * 3 + 1], x2 = x[(size_t)i * 3 + 2];
#pragma unroll
    for (int o = 0; o < H; ++o)
        r[o] = fmaf(x2, W_in[2 * H + o], fmaf(x1, W_in[1 * H + o], fmaf(x0, W_in[0 * H + o], b_in[o])));
}

// ---------------- kernel 0: zero the aggregation tables ----------------
__global__ __launch_bounds__(256) void zero_kernel(float* __restrict__ p, size_t n) {
    size_t i = (size_t)blockIdx.x * blockDim.x + threadIdx.x;
    size_t stride = (size_t)gridDim.x * blockDim.x;
    for (; i < n; i += stride) p[i] = 0.0f;
}

// ---------------- kernel 1: encoded -> atomic aggr_msgs[dst] ----------------
__global__ __launch_bounds__(256) void edge_pass1_kernel(const float* __restrict__ h_msg,
                                                         const int* __restrict__ eidx,
                                                         const float* __restrict__ We,
                                                         const float* __restrict__ be,
                                                         float* __restrict__ aggr_msgs) {
    int e = blockIdx.x * blockDim.x + threadIdx.x;
    if (e >= N_EDGES) return;
    float m[H], enc[H];
    load_row32(h_msg + (size_t)e * H, m);
    matvec32(m, We, be, enc);
    int dst = eidx[(size_t)N_EDGES + e];
    float* ap = aggr_msgs + (size_t)dst * H;
#pragma unroll
    for (int o = 0; o < H; ++o) atomicAdd(ap + o, enc[o]);
}

// ---------------- kernel 2: per-edge message + outputs + aggr_out ----------------
__global__ __launch_bounds__(256) void edge_pass2_kernel(
    const float* __restrict__ h_msg, const int* __restrict__ eidx,
    const float* __restrict__ x, const float* __restrict__ aggr_msgs,
    const float* __restrict__ W_in, const float* __restrict__ b_in,
    const float* __restrict__ We, const float* __restrict__ be,
    const float* __restrict__ Wn1, const float* __restrict__ bn1,
    const float* __restrict__ Wn2, const float* __restrict__ bn2,
    const float* __restrict__ WN1, const float* __restrict__ bN1,
    const float* __restrict__ WN2, const float* __restrict__ bN2,
    const float* __restrict__ Wd, const float* __restrict__ bd,
    float* __restrict__ aggr_out,
    float* __restrict__ out_hmsg, float* __restrict__ out_ymsg) {
    int e = blockIdx.x * blockDim.x + threadIdx.x;
    if (e >= N_EDGES) return;

    int src = eidx[e];
    int dst = eidx[(size_t)N_EDGES + e];

    float buf0[H], buf1[H], enc[H], nn[H];

    // encoded = h_msg[e] @ We + be
    load_row32(h_msg + (size_t)e * H, buf0);
    matvec32(buf0, We, be, enc);

    // nn = lrelu(lrelu(h_node[src] @ Wn1 + bn1) @ Wn2 + bn2); h_node recomputed from x
    hnode_row(x, src, W_in, b_in, buf0);
    matvec32(buf0, Wn1, bn1, buf1);
#pragma unroll
    for (int o = 0; o < H; ++o) buf1[o] = lrelu(buf1[o]);
    matvec32(buf1, Wn2, bn2, nn);
#pragma unroll
    for (int o = 0; o < H; ++o) nn[o] = lrelu(nn[o]);

    // n_out = lrelu(lrelu([aggr_msgs[src], enc] @ WN1 + bN1) @ WN2 + bN2)
    load_row32(aggr_msgs + (size_t)src * H, buf0);
    matvec32(buf0, WN1, bN1, buf1);          // top half of WN1
    matvec32_acc(enc, WN1 + H * H, buf1);    // bottom half of WN1
#pragma unroll
    for (int o = 0; o < H; ++o) buf1[o] = lrelu(buf1[o]);
    matvec32(buf1, WN2, bN2, buf0);
#pragma unroll
    for (int o = 0; o < H; ++o) nn[o] += lrelu(buf0[o]);   // h_msg_new

    // write h_msg_new
    store_row32(out_hmsg + (size_t)e * H, nn);

    // scatter into aggr_out[dst]
    float* ap = aggr_out + (size_t)dst * H;
#pragma unroll
    for (int o = 0; o < H; ++o) atomicAdd(ap + o, nn[o]);

    // y_msg = softmax(h_msg_new @ Wd + bd)
    float z0 = bd[0], z1 = bd[1];
#pragma unroll
    for (int k = 0; k < H; ++k) {
        z0 = fmaf(nn[k], Wd[k * 2 + 0], z0);
        z1 = fmaf(nn[k], Wd[k * 2 + 1], z1);
    }
    float zm = fmaxf(z0, z1);
    float e0 = __expf(z0 - zm), e1 = __expf(z1 - zm);
    float inv = 1.0f / (e0 + e1);
    out_ymsg[(size_t)e * 2 + 0] = e0 * inv;
    out_ymsg[(size_t)e * 2 + 1] = e1 * inv;
}

// ---------------- kernel 3: node update + beliefs ----------------
__global__ __launch_bounds__(256) void node_update_kernel(
    const float* __restrict__ x, const float* __restrict__ aggr_out,
    const float* __restrict__ W_in, const float* __restrict__ b_in,
    const float* __restrict__ WU, const float* __restrict__ bU,
    const float* __restrict__ Wb, const float* __restrict__ bb,
    float* __restrict__ out_beliefs) {
    int i = blockIdx.x * blockDim.x + threadIdx.x;
    if (i >= N_NODES) return;
    float a[H], t[H];
    // t = lrelu([h_node, aggr_out] @ WU + bU); h_node recomputed from x
    hnode_row(x, i, W_in, b_in, a);
    matvec32(a, WU, bU, t);
    load_row32(aggr_out + (size_t)i * H, a);
    matvec32_acc(a, WU + H * H, t);
#pragma unroll
    for (int o = 0; o < H; ++o) t[o] = lrelu(t[o]);

    // beliefs only for variable nodes (x[:,0]==1, contiguous prefix -> out row == i)
    if (x[(size_t)i * 3] == 1.0f) {
        float z0 = bb[0], z1 = bb[1];
#pragma unroll
        for (int k = 0; k < H; ++k) {
            z0 = fmaf(t[k], Wb[k * 2 + 0], z0);
            z1 = fmaf(t[k], Wb[k * 2 + 1], z1);
        }
        float zm = fmaxf(z0, z1);
        float e0 = __expf(z0 - zm), e1 = __expf(z1 - zm);
        float inv = 1.0f / (e0 + e1);
        out_beliefs[(size_t)i * 2 + 0] = e0 * inv;
        out_beliefs[(size_t)i * 2 + 1] = e1 * inv;
    }
}

extern "C" void kernel_launch(void* const* d_in, const int* in_sizes, int n_in,
                              void* d_out, int out_size, void* d_ws, size_t ws_size,
                              hipStream_t stream) {
    const float* x     = (const float*)d_in[0];
    const int*   eidx  = (const int*)d_in[1];
    const float* h_msg = (const float*)d_in[2];
    const float* W_in = (const float*)d_in[3];  const float* b_in = (const float*)d_in[4];
    const float* We   = (const float*)d_in[5];  const float* be   = (const float*)d_in[6];
    const float* Wn1  = (const float*)d_in[7];  const float* bn1  = (const float*)d_in[8];
    const float* Wn2  = (const float*)d_in[9];  const float* bn2  = (const float*)d_in[10];
    const float* WN1  = (const float*)d_in[11]; const float* bN1  = (const float*)d_in[12];
    const float* WN2  = (const float*)d_in[13]; const float* bN2  = (const float*)d_in[14];
    const float* WU   = (const float*)d_in[15]; const float* bU   = (const float*)d_in[16];
    const float* Wd   = (const float*)d_in[17]; const float* bd   = (const float*)d_in[18];
    const float* Wb   = (const float*)d_in[19]; const float* bb   = (const float*)d_in[20];

    float* out         = (float*)d_out;
    float* out_hmsg    = out;
    float* out_ymsg    = out + (size_t)N_EDGES * H;
    float* out_beliefs = out + (size_t)N_EDGES * (H + 2);

    float* aggr_msgs = (float*)d_ws;                          // [N, H]
    float* aggr_out  = aggr_msgs + (size_t)N_NODES * H;       // [N, H]

    // zero the two accumulation tables (must happen every launch)
    zero_kernel<<<2048, 256, 0, stream>>>((float*)d_ws, (size_t)2 * N_NODES * H);

    edge_pass1_kernel<<<(N_EDGES + 255) / 256, 256, 0, stream>>>(h_msg, eidx, We, be, aggr_msgs);

    edge_pass2_kernel<<<(N_EDGES + 255) / 256, 256, 0, stream>>>(
        h_msg, eidx, x, aggr_msgs,
        W_in, b_in, We, be, Wn1, bn1, Wn2, bn2, WN1, bN1, WN2, bN2, Wd, bd,
        aggr_out, out_hmsg, out_ymsg);

    node_update_kernel<<<(N_NODES + 255) / 256, 256, 0, stream>>>(
        x, aggr_out, W_in, b_in, WU, bU, Wb, bb, out_beliefs);
}

// Round 3
// 1878.936 us; speedup vs baseline: 5.8036x; 5.8036x over previous
//
#include <hip/hip_runtime.h>
#include <math.h>

#define N_NODES 100000
#define N_EDGES 3200000
#define H 32

__device__ __forceinline__ float lrelu(float v) { return v > 0.0f ? v : 0.01f * v; }

// out = bias + in @ W   (W is [H,H] row-major: W[k*H+o]); uniform W/bias -> s_loads
__device__ __forceinline__ void matvec32(const float* __restrict__ in,
                                         const float* __restrict__ W,
                                         const float* __restrict__ bias,
                                         float* __restrict__ out) {
#pragma unroll
    for (int o = 0; o < H; ++o) out[o] = bias[o];
#pragma unroll
    for (int k = 0; k < H; ++k) {
        float v = in[k];
#pragma unroll
        for (int o = 0; o < H; ++o) out[o] = fmaf(v, W[k * H + o], out[o]);
    }
}

// out += in @ W
__device__ __forceinline__ void matvec32_acc(const float* __restrict__ in,
                                             const float* __restrict__ W,
                                             float* __restrict__ out) {
#pragma unroll
    for (int k = 0; k < H; ++k) {
        float v = in[k];
#pragma unroll
        for (int o = 0; o < H; ++o) out[o] = fmaf(v, W[k * H + o], out[o]);
    }
}

__device__ __forceinline__ void load_row32(const float* __restrict__ p, float* __restrict__ r) {
    const float4* p4 = reinterpret_cast<const float4*>(p);
#pragma unroll
    for (int q = 0; q < 8; ++q) {
        float4 v = p4[q];
        r[4 * q + 0] = v.x; r[4 * q + 1] = v.y; r[4 * q + 2] = v.z; r[4 * q + 3] = v.w;
    }
}

__device__ __forceinline__ void store_row32(float* __restrict__ p, const float* __restrict__ r) {
    float4* p4 = reinterpret_cast<float4*>(p);
#pragma unroll
    for (int q = 0; q < 8; ++q) {
        float4 v;
        v.x = r[4 * q + 0]; v.y = r[4 * q + 1]; v.z = r[4 * q + 2]; v.w = r[4 * q + 3];
        p4[q] = v;
    }
}

// h_node row for node i from x[i] (W_in is [3,H])
__device__ __forceinline__ void hnode_row(const float* __restrict__ x, int i,
                                          const float* __restrict__ W_in,
                                          const float* __restrict__ b_in,
                                          float* __restrict__ r) {
    float x0 = x[(size_t)i * 3 + 0], x1 = x[(size_t)i * 3 + 1], x2 = x[(size_t)i * 3 + 2];
#pragma unroll
    for (int o = 0; o < H; ++o)
        r[o] = fmaf(x2, W_in[2 * H + o], fmaf(x1, W_in[1 * H + o], fmaf(x0, W_in[0 * H + o], b_in[o])));
}

// ---------------- CSR build ----------------
__global__ __launch_bounds__(256) void zero_int_kernel(int* __restrict__ p, int n) {
    int i = blockIdx.x * blockDim.x + threadIdx.x;
    if (i < n) p[i] = 0;
}

__global__ __launch_bounds__(256) void hist_kernel(const int* __restrict__ eidx, int* __restrict__ cnt) {
    int e = blockIdx.x * blockDim.x + threadIdx.x;
    if (e >= N_EDGES) return;
    atomicAdd(&cnt[eidx[(size_t)N_EDGES + e]], 1);
}

// single-block exclusive scan over cnt[0..N_NODES) -> ptr[0..N_NODES]
__global__ __launch_bounds__(1024) void scan_kernel(const int* __restrict__ cnt, int* __restrict__ ptr) {
    __shared__ int smem[1024];
    __shared__ int s_carry;
    int tid = threadIdx.x;
    if (tid == 0) s_carry = 0;
    __syncthreads();
    for (int base = 0; base < N_NODES; base += 1024) {
        int idx = base + tid;
        int v = (idx < N_NODES) ? cnt[idx] : 0;
        smem[tid] = v;
        __syncthreads();
        for (int off = 1; off < 1024; off <<= 1) {
            int t = (tid >= off) ? smem[tid - off] : 0;
            __syncthreads();
            smem[tid] += t;
            __syncthreads();
        }
        int carry = s_carry;
        if (idx < N_NODES) ptr[idx] = carry + smem[tid] - v;
        __syncthreads();
        if (tid == 1023) s_carry = carry + smem[1023];
        __syncthreads();
    }
    if (tid == 0) ptr[N_NODES] = s_carry;
}

__global__ __launch_bounds__(256) void scatter_kernel(const int* __restrict__ eidx,
                                                      const int* __restrict__ ptr,
                                                      int* __restrict__ fill,
                                                      int* __restrict__ sorted) {
    int e = blockIdx.x * blockDim.x + threadIdx.x;
    if (e >= N_EDGES) return;
    int dst = eidx[(size_t)N_EDGES + e];
    int pos = atomicAdd(&fill[dst], 1);
    sorted[ptr[dst] + pos] = e;
}

// ---------------- encode: enc = h_msg @ We + be  (written into d_out's h_msg region as temp) ----------------
__global__ __launch_bounds__(256) void encode_kernel(const float* __restrict__ h_msg,
                                                     const float* __restrict__ We,
                                                     const float* __restrict__ be,
                                                     float* __restrict__ enc_out) {
    int e = blockIdx.x * blockDim.x + threadIdx.x;
    if (e >= N_EDGES) return;
    float m[H], enc[H];
    load_row32(h_msg + (size_t)e * H, m);
    matvec32(m, We, be, enc);
    store_row32(enc_out + (size_t)e * H, enc);
}

// ---------------- CSR gather-reduce: out[n][c] = sum over incoming edges of rows[eid][c] ----------------
__global__ __launch_bounds__(256) void aggr_kernel(const float* __restrict__ rows,
                                                   const int* __restrict__ ptr,
                                                   const int* __restrict__ sorted,
                                                   float* __restrict__ out) {
    int t = blockIdx.x * blockDim.x + threadIdx.x;
    int n = t >> 5, c = t & 31;
    if (n >= N_NODES) return;
    int b = ptr[n], e = ptr[n + 1];
    float acc = 0.0f;
    for (int i = b; i < e; ++i) acc += rows[(size_t)sorted[i] * H + c];
    out[(size_t)n * H + c] = acc;
}

// ---------------- pass2: per-edge message + outputs (no atomics) ----------------
__global__ __launch_bounds__(256) void edge_pass2_kernel(
    const int* __restrict__ eidx,
    const float* __restrict__ x, const float* __restrict__ aggr_msgs,
    const float* __restrict__ W_in, const float* __restrict__ b_in,
    const float* __restrict__ Wn1, const float* __restrict__ bn1,
    const float* __restrict__ Wn2, const float* __restrict__ bn2,
    const float* __restrict__ WN1, const float* __restrict__ bN1,
    const float* __restrict__ WN2, const float* __restrict__ bN2,
    const float* __restrict__ Wd, const float* __restrict__ bd,
    float* __restrict__ out_hmsg, float* __restrict__ out_ymsg) {
    int e = blockIdx.x * blockDim.x + threadIdx.x;
    if (e >= N_EDGES) return;

    int src = eidx[e];

    float buf0[H], buf1[H], enc[H], nn[H];

    // encoded was precomputed into out_hmsg[e] (this thread's own row; safe to overwrite later)
    load_row32(out_hmsg + (size_t)e * H, enc);

    // nn = lrelu(lrelu(h_node[src] @ Wn1 + bn1) @ Wn2 + bn2); h_node recomputed from x
    hnode_row(x, src, W_in, b_in, buf0);
    matvec32(buf0, Wn1, bn1, buf1);
#pragma unroll
    for (int o = 0; o < H; ++o) buf1[o] = lrelu(buf1[o]);
    matvec32(buf1, Wn2, bn2, nn);
#pragma unroll
    for (int o = 0; o < H; ++o) nn[o] = lrelu(nn[o]);

    // n_out = lrelu(lrelu([aggr_msgs[src], enc] @ WN1 + bN1) @ WN2 + bN2)
    load_row32(aggr_msgs + (size_t)src * H, buf0);
    matvec32(buf0, WN1, bN1, buf1);          // top half of WN1
    matvec32_acc(enc, WN1 + H * H, buf1);    // bottom half of WN1
#pragma unroll
    for (int o = 0; o < H; ++o) buf1[o] = lrelu(buf1[o]);
    matvec32(buf1, WN2, bN2, buf0);
#pragma unroll
    for (int o = 0; o < H; ++o) nn[o] += lrelu(buf0[o]);   // h_msg_new

    // overwrite encoded with h_msg_new
    store_row32(out_hmsg + (size_t)e * H, nn);

    // y_msg = softmax(h_msg_new @ Wd + bd)
    float z0 = bd[0], z1 = bd[1];
#pragma unroll
    for (int k = 0; k < H; ++k) {
        z0 = fmaf(nn[k], Wd[k * 2 + 0], z0);
        z1 = fmaf(nn[k], Wd[k * 2 + 1], z1);
    }
    float zm = fmaxf(z0, z1);
    float e0 = __expf(z0 - zm), e1 = __expf(z1 - zm);
    float inv = 1.0f / (e0 + e1);
    out_ymsg[(size_t)e * 2 + 0] = e0 * inv;
    out_ymsg[(size_t)e * 2 + 1] = e1 * inv;
}

// ---------------- node update + beliefs ----------------
__global__ __launch_bounds__(256) void node_update_kernel(
    const float* __restrict__ x, const float* __restrict__ aggr_out,
    const float* __restrict__ W_in, const float* __restrict__ b_in,
    const float* __restrict__ WU, const float* __restrict__ bU,
    const float* __restrict__ Wb, const float* __restrict__ bb,
    float* __restrict__ out_beliefs) {
    int i = blockIdx.x * blockDim.x + threadIdx.x;
    if (i >= N_NODES) return;
    float a[H], t[H];
    hnode_row(x, i, W_in, b_in, a);
    matvec32(a, WU, bU, t);
    load_row32(aggr_out + (size_t)i * H, a);
    matvec32_acc(a, WU + H * H, t);
#pragma unroll
    for (int o = 0; o < H; ++o) t[o] = lrelu(t[o]);

    // beliefs only for variable nodes (x[:,0]==1, contiguous prefix -> out row == i)
    if (x[(size_t)i * 3] == 1.0f) {
        float z0 = bb[0], z1 = bb[1];
#pragma unroll
        for (int k = 0; k < H; ++k) {
            z0 = fmaf(t[k], Wb[k * 2 + 0], z0);
            z1 = fmaf(t[k], Wb[k * 2 + 1], z1);
        }
        float zm = fmaxf(z0, z1);
        float e0 = __expf(z0 - zm), e1 = __expf(z1 - zm);
        float inv = 1.0f / (e0 + e1);
        out_beliefs[(size_t)i * 2 + 0] = e0 * inv;
        out_beliefs[(size_t)i * 2 + 1] = e1 * inv;
    }
}

extern "C" void kernel_launch(void* const* d_in, const int* in_sizes, int n_in,
                              void* d_out, int out_size, void* d_ws, size_t ws_size,
                              hipStream_t stream) {
    const float* x     = (const float*)d_in[0];
    const int*   eidx  = (const int*)d_in[1];
    const float* h_msg = (const float*)d_in[2];
    const float* W_in = (const float*)d_in[3];  const float* b_in = (const float*)d_in[4];
    const float* We   = (const float*)d_in[5];  const float* be   = (const float*)d_in[6];
    const float* Wn1  = (const float*)d_in[7];  const float* bn1  = (const float*)d_in[8];
    const float* Wn2  = (const float*)d_in[9];  const float* bn2  = (const float*)d_in[10];
    const float* WN1  = (const float*)d_in[11]; const float* bN1  = (const float*)d_in[12];
    const float* WN2  = (const float*)d_in[13]; const float* bN2  = (const float*)d_in[14];
    const float* WU   = (const float*)d_in[15]; const float* bU   = (const float*)d_in[16];
    const float* Wd   = (const float*)d_in[17]; const float* bd   = (const float*)d_in[18];
    const float* Wb   = (const float*)d_in[19]; const float* bb   = (const float*)d_in[20];

    float* out         = (float*)d_out;
    float* out_hmsg    = out;                                  // also used as `encoded` temp
    float* out_ymsg    = out + (size_t)N_EDGES * H;
    float* out_beliefs = out + (size_t)N_EDGES * (H + 2);

    // workspace layout
    float* aggr_msgs = (float*)d_ws;                           // [N, H] 12.8 MB
    float* aggr_out  = aggr_msgs + (size_t)N_NODES * H;        // [N, H] 12.8 MB
    int*   cnt       = (int*)(aggr_out + (size_t)N_NODES * H); // [N]
    int*   ptr       = cnt + N_NODES;                          // [N+1]
    int*   fill      = ptr + (N_NODES + 1);                    // [N]
    int*   sorted    = fill + N_NODES;                         // [E] 12.8 MB

    const int EB = (N_EDGES + 255) / 256;
    const int NB32 = (N_NODES * H + 255) / 256;   // (node,channel) threads

    // --- CSR build (by dst) ---
    zero_int_kernel<<<(2 * N_NODES + 256) / 256, 256, 0, stream>>>(cnt, 2 * N_NODES + 1); // cnt+ptr+fill are contiguous? no — zero cnt & fill separately
    // NOTE: cnt,ptr,fill are laid out consecutively: cnt[N], ptr[N+1], fill[N].
    // The call above zeros cnt[0..N) and ptr[0..N+1) partially; zero fill explicitly:
    zero_int_kernel<<<(N_NODES + 255) / 256, 256, 0, stream>>>(fill, N_NODES);
    hist_kernel<<<EB, 256, 0, stream>>>(eidx, cnt);
    scan_kernel<<<1, 1024, 0, stream>>>(cnt, ptr);
    scatter_kernel<<<EB, 256, 0, stream>>>(eidx, ptr, fill, sorted);

    // --- encoded into out_hmsg (temp) ---
    encode_kernel<<<EB, 256, 0, stream>>>(h_msg, We, be, out_hmsg);

    // --- aggr_msgs = segment_sum(encoded, dst) ---
    aggr_kernel<<<NB32, 256, 0, stream>>>(out_hmsg, ptr, sorted, aggr_msgs);

    // --- per-edge messages (overwrites out_hmsg with h_msg_new) ---
    edge_pass2_kernel<<<EB, 256, 0, stream>>>(
        eidx, x, aggr_msgs,
        W_in, b_in, Wn1, bn1, Wn2, bn2, WN1, bN1, WN2, bN2, Wd, bd,
        out_hmsg, out_ymsg);

    // --- aggr_out = segment_sum(h_msg_new, dst) ---
    aggr_kernel<<<NB32, 256, 0, stream>>>(out_hmsg, ptr, sorted, aggr_out);

    // --- node update + beliefs ---
    node_update_kernel<<<(N_NODES + 255) / 256, 256, 0, stream>>>(
        x, aggr_out, W_in, b_in, WU, bU, Wb, bb, out_beliefs);
}